// Round 9
// baseline (221.258 us; speedup 1.0000x reference)
//
#include <hip/hip_runtime.h>
#include <hip/hip_bf16.h>

constexpr int BATCH = 32768;
constexpr int KDIM  = 128;    // IN_F
constexpr int NDIM  = 2048;   // OUT_F

using f32x4  = __attribute__((ext_vector_type(4))) float;
using bf16x8 = __attribute__((ext_vector_type(8))) short;

// ---------------------------------------------------------------------------
// Fragment order for mfma_f32_16x16x32_bf16 (verified R2/R3):
//   A (MxK): lane l holds m = l&15,  k(j) = 4*(l>>4) + (j&3) + 16*(j>>2)
//   B (KxN): lane l holds n = l&15,  same k(j)
//   D:       lane l holds col = l&15, row = (l>>4)*4 + reg
// 2-term split: z = (x_hi + x_lo) @ W_hi  (absmax ~8e-3 < 2e-2 threshold)
//
// R9: OPERAND SWAP. Feeding mfma(W_frag, x_frag) computes D = W^T x^T = z^T:
// lane l holds z[batch row = l&15][col = nt*16 + (l>>4)*4 + r]. Each lane owns
// 4 consecutive cols of ONE row -> pm gate and out store are per-lane aligned
// f32x4 (one instr = 16 fully-covered 64B segments). No LDS z-transpose, no
// chunk barriers, no bank conflicts. Row reduce = 2 shuffles + tiny LDS
// combine across 8 waves. LDS 64KB -> 2KB static.
// ---------------------------------------------------------------------------

__device__ inline void split_bf16(float v, ushort& hi, ushort& lo) {
    __hip_bfloat16 h = __float2bfloat16(v);
    float r = v - __bfloat162float(h);
    __hip_bfloat16 l = __float2bfloat16(r);
    hi = *reinterpret_cast<ushort*>(&h);
    lo = *reinterpret_cast<ushort*>(&l);
}

// W [128][2048] -> Bh[nt=128][kk=4][lane=64][j=8]  (hi only)
__global__ __launch_bounds__(256)
void conv_w_kernel(const float* __restrict__ W, ushort* __restrict__ Bh) {
    int id = blockIdx.x * 256 + threadIdx.x;      // 0 .. 262143
    int j  = id & 7;
    int l  = (id >> 3) & 63;
    int kk = (id >> 9) & 3;
    int nt = id >> 11;
    int k  = kk * 32 + 4 * (l >> 4) + (j & 3) + 16 * (j >> 2);
    int n  = nt * 16 + (l & 15);
    __hip_bfloat16 h = __float2bfloat16(W[k * NDIM + n]);
    Bh[id] = *reinterpret_cast<ushort*>(&h);
}

// x [32768][128] -> A{h,l}[rt=2048][kk=4][lane=64][j=8]
__global__ __launch_bounds__(256)
void conv_x_kernel(const float* __restrict__ x,
                   ushort* __restrict__ Ah, ushort* __restrict__ Al) {
    int id = blockIdx.x * 256 + threadIdx.x;      // 0 .. 4194303
    int j  = id & 7;
    int l  = (id >> 3) & 63;
    int kk = (id >> 9) & 3;
    int rt = id >> 11;
    int k  = kk * 32 + 4 * (l >> 4) + (j & 3) + 16 * (j >> 2);
    int m  = rt * 16 + (l & 15);
    ushort hi, lo;
    split_bf16(x[m * KDIM + k], hi, lo);
    Ah[id] = hi; Al[id] = lo;
}

// ---------------------------------------------------------------------------
// Main: grid 2048, 512 thr (8 waves), 16 rows x 2048 cols per block.
// Wave q: col tiles q*16..q*16+15 (swapped-operand MFMA, acc[16] f32x4).
// Lane l owns row l&15, cols {q*256 + t*16 + (l>>4)*4 + r}.
// Michelot: per-lane partials -> shfl_xor(16,32) -> red[2][8][16] LDS combine,
// __syncthreads_and convergence (2 barriers/iter, double-buffered).
// ---------------------------------------------------------------------------
constexpr int GRID = BATCH / 16;                // 2048

__global__ __launch_bounds__(512, 4)
void mfma_sparsemax_swapped(const ushort* __restrict__ Ah, const ushort* __restrict__ Al,
                            const ushort* __restrict__ Bh,
                            const float* __restrict__ pm, float* __restrict__ out) {
    __shared__ float2 red[2][8][16];            // [buf][wave][row], 2 KB

    const int tid = threadIdx.x;
    const int l   = tid & 63;
    const int q   = tid >> 6;                   // wave id 0..7
    const int g   = l >> 4;
    const int m0  = l & 15;                     // my batch row (local)
    const int rt  = blockIdx.x;
    const long grow = (long)rt * 16 + m0;       // my batch row (global)

    const bf16x8* A8h = reinterpret_cast<const bf16x8*>(Ah);
    const bf16x8* A8l = reinterpret_cast<const bf16x8*>(Al);
    const bf16x8* B8h = reinterpret_cast<const bf16x8*>(Bh);

    // ---- x fragments (16 rows of this tile) ----
    bf16x8 ah[4], al[4];
    #pragma unroll
    for (int kk = 0; kk < 4; ++kk) {
        ah[kk] = A8h[(rt * 4 + kk) * 64 + l];
        al[kk] = A8l[(rt * 4 + kk) * 64 + l];
    }

    // ---- GEMM, swapped operands: acc[t][r] = z[grow][q*256 + t*16 + g*4 + r]
    f32x4 acc[16];
    #pragma unroll
    for (int t = 0; t < 16; ++t) {
        const int nt = q * 16 + t;
        f32x4 c = {0.f, 0.f, 0.f, 0.f};
        #pragma unroll
        for (int kk = 0; kk < 4; ++kk) {
            bf16x8 b = B8h[(nt * 4 + kk) * 64 + l];
            c = __builtin_amdgcn_mfma_f32_16x16x32_bf16(b, ah[kk], c, 0, 0, 0);
            c = __builtin_amdgcn_mfma_f32_16x16x32_bf16(b, al[kk], c, 0, 0, 0);
        }
        acc[t] = c;
    }

    // ---- gate by prev_mask: per-lane aligned f32x4 loads ----
    const float* pmbase = pm + grow * NDIM + q * 256 + g * 4;
    #pragma unroll
    for (int t = 0; t < 16; ++t) {
        f32x4 p = *reinterpret_cast<const f32x4*>(pmbase + t * 16);
        acc[t] *= p;
    }

    // ---- init: row max & sum ----
    float mx = acc[0][0], sm = 0.f;
    #pragma unroll
    for (int t = 0; t < 16; ++t)
        #pragma unroll
        for (int r = 0; r < 4; ++r) { float v = acc[t][r]; mx = fmaxf(mx, v); sm += v; }
    mx = fmaxf(mx, __shfl_xor(mx, 16, 64));
    mx = fmaxf(mx, __shfl_xor(mx, 32, 64));
    sm += __shfl_xor(sm, 16, 64);
    sm += __shfl_xor(sm, 32, 64);
    if (l < 16) red[0][q][l] = make_float2(mx, sm);
    __syncthreads();
    float M = -1e30f, S = 0.f;
    #pragma unroll
    for (int w = 0; w < 8; ++w) { float2 e = red[0][w][m0]; M = fmaxf(M, e.x); S += e.y; }
    float tau = fmaxf(M - 1.f, (S - 1.f) * (1.f / 2048.f));
    float cprev = -1.f;

    // ---- Michelot fixed-point, block-wide (all 16 rows together) ----
    for (int it = 0; it < 32; ++it) {
        float ps = 0.f, pc = 0.f;
        #pragma unroll
        for (int t = 0; t < 16; ++t)
            #pragma unroll
            for (int r = 0; r < 4; ++r) {
                float v = acc[t][r];
                bool a = v > tau;
                ps += a ? v : 0.f;
                pc += a ? 1.f : 0.f;
            }
        ps += __shfl_xor(ps, 16, 64);
        ps += __shfl_xor(ps, 32, 64);
        pc += __shfl_xor(pc, 16, 64);
        pc += __shfl_xor(pc, 32, 64);
        const int buf = (it + 1) & 1;
        if (l < 16) red[buf][q][l] = make_float2(ps, pc);
        __syncthreads();
        float SS = 0.f, CC = 0.f;
        #pragma unroll
        for (int w = 0; w < 8; ++w) { float2 e = red[buf][w][m0]; SS += e.x; CC += e.y; }
        tau = (SS - 1.f) / CC;                  // CC >= 1 always
        int done = (CC == cprev);               // count stable -> fixpoint (nested sets)
        cprev = CC;
        if (__syncthreads_and(done)) break;
    }

    // ---- out = max(z - tau, 0): per-lane aligned f32x4 stores ----
    float* obase = out + grow * NDIM + q * 256 + g * 4;
    #pragma unroll
    for (int t = 0; t < 16; ++t) {
        f32x4 v = acc[t];
        f32x4 o;
        o.x = fmaxf(v.x - tau, 0.f);
        o.y = fmaxf(v.y - tau, 0.f);
        o.z = fmaxf(v.z - tau, 0.f);
        o.w = fmaxf(v.w - tau, 0.f);
        *reinterpret_cast<f32x4*>(obase + t * 16) = o;
    }
}

// ---------------------------------------------------------------------------
// Fallback (R1 kernel) if d_ws too small.
// ---------------------------------------------------------------------------
__device__ inline float wave_sum(float v) {
    #pragma unroll
    for (int off = 32; off > 0; off >>= 1) v += __shfl_xor(v, off, 64);
    return v;
}

__global__ __launch_bounds__(256)
void fused_sparsemax_fallback(const float* __restrict__ x,
                              const float* __restrict__ pm,
                              const float* __restrict__ W,
                              float* __restrict__ out) {
    __shared__ float xs[8][KDIM];
    __shared__ float zsf[4][NDIM];
    const int tid  = threadIdx.x;
    const int lane = tid & 63;
    const int wv   = tid >> 6;
    const long r0  = (long)blockIdx.x * 8;
    {
        const float4* src = reinterpret_cast<const float4*>(x + r0 * KDIM);
        reinterpret_cast<float4*>(&xs[0][0])[tid] = src[tid];
    }
    __syncthreads();
    float acc[8][8];
    #pragma unroll
    for (int r = 0; r < 8; ++r)
        #pragma unroll
        for (int j = 0; j < 8; ++j) acc[r][j] = 0.f;
    const float4* Wv4 = reinterpret_cast<const float4*>(W);
    #pragma unroll 4
    for (int k = 0; k < KDIM; ++k) {
        const float4 w0 = Wv4[k * (NDIM / 4) + tid];
        const float4 w1 = Wv4[k * (NDIM / 4) + 256 + tid];
        #pragma unroll
        for (int r = 0; r < 8; ++r) {
            const float xv = xs[r][k];
            acc[r][0] = fmaf(xv, w0.x, acc[r][0]);
            acc[r][1] = fmaf(xv, w0.y, acc[r][1]);
            acc[r][2] = fmaf(xv, w0.z, acc[r][2]);
            acc[r][3] = fmaf(xv, w0.w, acc[r][3]);
            acc[r][4] = fmaf(xv, w1.x, acc[r][4]);
            acc[r][5] = fmaf(xv, w1.y, acc[r][5]);
            acc[r][6] = fmaf(xv, w1.z, acc[r][6]);
            acc[r][7] = fmaf(xv, w1.w, acc[r][7]);
        }
    }
    const float4* pmv = reinterpret_cast<const float4*>(pm);
    #pragma unroll
    for (int half = 0; half < 2; ++half) {
        __syncthreads();
        #pragma unroll
        for (int rr = 0; rr < 4; ++rr) {
            const int r = half * 4 + rr;
            const long rowbase4 = (r0 + r) * (NDIM / 4);
            const float4 m0 = pmv[rowbase4 + tid];
            const float4 m1 = pmv[rowbase4 + 256 + tid];
            float4 z0, z1;
            z0.x = acc[r][0] * m0.x; z0.y = acc[r][1] * m0.y;
            z0.z = acc[r][2] * m0.z; z0.w = acc[r][3] * m0.w;
            z1.x = acc[r][4] * m1.x; z1.y = acc[r][5] * m1.y;
            z1.z = acc[r][6] * m1.z; z1.w = acc[r][7] * m1.w;
            float4* zr = reinterpret_cast<float4*>(&zsf[rr][0]);
            zr[tid] = z0; zr[256 + tid] = z1;
        }
        __syncthreads();
        float zvv[32];
        const float4* zr = reinterpret_cast<const float4*>(&zsf[wv][0]);
        #pragma unroll
        for (int cc = 0; cc < 8; ++cc) {
            const float4 v = zr[cc * 64 + lane];
            zvv[cc * 4 + 0] = v.x; zvv[cc * 4 + 1] = v.y;
            zvv[cc * 4 + 2] = v.z; zvv[cc * 4 + 3] = v.w;
        }
        float s = 0.f;
        #pragma unroll
        for (int i = 0; i < 32; ++i) s += zvv[i];
        s = wave_sum(s);
        float tau = (s - 1.f) / 2048.f;
        float cprev = 2048.f;
        for (int itf = 0; itf < 64; ++itf) {
            float ps = 0.f, pc = 0.f;
            #pragma unroll
            for (int i = 0; i < 32; ++i)
                if (zvv[i] > tau) { ps += zvv[i]; pc += 1.f; }
            ps = wave_sum(ps);
            pc = wave_sum(pc);
            tau = (ps - 1.f) / pc;
            if (pc == cprev) break;
            cprev = pc;
        }
        float4* orow = reinterpret_cast<float4*>(out + (r0 + half * 4 + wv) * NDIM);
        #pragma unroll
        for (int cc = 0; cc < 8; ++cc) {
            float4 v;
            v.x = fmaxf(zvv[cc * 4 + 0] - tau, 0.f);
            v.y = fmaxf(zvv[cc * 4 + 1] - tau, 0.f);
            v.z = fmaxf(zvv[cc * 4 + 2] - tau, 0.f);
            v.w = fmaxf(zvv[cc * 4 + 3] - tau, 0.f);
            orow[cc * 64 + lane] = v;
        }
    }
}

extern "C" void kernel_launch(void* const* d_in, const int* in_sizes, int n_in,
                              void* d_out, int out_size, void* d_ws, size_t ws_size,
                              hipStream_t stream) {
    const float* x  = (const float*)d_in[0];   // [32768, 128]
    const float* pm = (const float*)d_in[1];   // [32768, 2048]
    const float* W  = (const float*)d_in[2];   // [128, 2048]
    float* out = (float*)d_out;

    const size_t szA = (size_t)BATCH * KDIM * sizeof(ushort);   // 8 MB each
    const size_t szB = (size_t)KDIM * NDIM * sizeof(ushort);    // 512 KB
    const size_t need = 2 * szA + szB;

    if (ws_size >= need) {
        char* base = (char*)d_ws;
        ushort* Ah = (ushort*)(base);
        ushort* Al = (ushort*)(base + szA);
        ushort* Bh = (ushort*)(base + 2 * szA);

        conv_x_kernel<<<(BATCH * KDIM) / 256, 256, 0, stream>>>(x, Ah, Al);
        conv_w_kernel<<<(KDIM * NDIM) / 256, 256, 0, stream>>>(W, Bh);
        mfma_sparsemax_swapped<<<GRID, 512, 0, stream>>>(Ah, Al, Bh, pm, out);
    } else {
        fused_sparsemax_fallback<<<BATCH / 8, 256, 0, stream>>>(x, pm, W, out);
    }
}